// Round 1
// baseline (421.164 us; speedup 1.0000x reference)
//
#include <hip/hip_runtime.h>

// Problem constants (fixed by the reference)
#define B_   4
#define L_   4096
#define H_   1024
#define N_   16
#define CH_  128            // scan chunk length
#define NC_  (L_/CH_)       // 32 chunks
#define M_   (B_*L_)        // 16384 GEMM rows
#define O2_  (2*H_)         // 2048 GEMM cols
#define EPS_ 1e-6f

typedef __attribute__((ext_vector_type(4))) float  f32x4;
typedef __attribute__((ext_vector_type(8))) __bf16 bf16x8;

__device__ __forceinline__ unsigned short f2bf(float x) {
  union { float f; unsigned int u; } v; v.f = x;
  unsigned int r = v.u + 0x7FFFu + ((v.u >> 16) & 1u);   // RNE
  return (unsigned short)(r >> 16);
}

__device__ __forceinline__ void async_copy16(const void* g, void* l) {
  __builtin_amdgcn_global_load_lds(
      (const __attribute__((address_space(1))) unsigned int*)g,
      (__attribute__((address_space(3))) unsigned int*)l, 16, 0, 0);
}

// ---------------- K0: SSM parameter precompute (H*N threads) ----------------
// w = exp(dt*A); Cd2 = 2*C*(exp(dt*A)-1)/A; wp = w^CH_ (for carry pass)
__global__ void k_params(const float* __restrict__ log_dt,
                         const float* __restrict__ log_A_real,
                         const float* __restrict__ A_imag,
                         const float* __restrict__ C_real,
                         const float* __restrict__ C_imag,
                         float* __restrict__ wr,  float* __restrict__ wi,
                         float* __restrict__ c2r, float* __restrict__ c2i,
                         float* __restrict__ wpr, float* __restrict__ wpi) {
  int idx = blockIdx.x * 256 + threadIdx.x;
  if (idx >= H_ * N_) return;
  int h = idx / N_, n = idx % N_;
  int hn = h * N_ + n;
  float dt  = expf(log_dt[h]);
  float Ar  = -expf(log_A_real[hn]);
  float Ai  = A_imag[hn];
  float dr  = Ar * dt, di = Ai * dt;          // dtA
  float er  = expf(dr);
  float wrv = er * cosf(di), wiv = er * sinf(di);   // w = exp(dtA)
  float e1r = wrv - 1.0f, e1i = wiv;                // exp(dtA)-1
  float den = Ar * Ar + Ai * Ai;
  float qr  = (e1r * Ar + e1i * Ai) / den;          // (exp(dtA)-1)/A
  float qi  = (e1i * Ar - e1r * Ai) / den;
  float Cr  = C_real[hn], Ci = C_imag[hn];
  float cdr = Cr * qr - Ci * qi;
  float cdi = Cr * qi + Ci * qr;
  float ep  = expf((float)CH_ * dr);
  int o = n * H_ + h;                                // [n][h] layout (lane-coalesced)
  wr[o]  = wrv;  wi[o]  = wiv;
  c2r[o] = 2.0f * cdr; c2i[o] = 2.0f * cdi;
  wpr[o] = ep * cosf((float)CH_ * di);
  wpi[o] = ep * sinf((float)CH_ * di);
}

// ---------------- K0b: out_w fp32 -> bf16 ----------------
__global__ void k_wbf(const float* __restrict__ w, unsigned short* __restrict__ wb) {
  int i = blockIdx.x * 256 + threadIdx.x;
  wb[i] = f2bf(w[i]);
}

// ---------------- K1: per-row RMSNorm scale = rsqrt(mean(h^2)+eps)*mask -----
__global__ __launch_bounds__(256) void k_scale(const float* __restrict__ hs,
                                               const float* __restrict__ mask,
                                               float* __restrict__ scale) {
  int m = blockIdx.x, tid = threadIdx.x;
  float4 v = reinterpret_cast<const float4*>(hs + (size_t)m * H_)[tid];
  float s = v.x * v.x + v.y * v.y + v.z * v.z + v.w * v.w;
  #pragma unroll
  for (int off = 32; off > 0; off >>= 1) s += __shfl_down(s, off, 64);
  __shared__ float ps[4];
  if ((tid & 63) == 0) ps[tid >> 6] = s;
  __syncthreads();
  if (tid == 0) {
    float var = (ps[0] + ps[1] + ps[2] + ps[3]) * (1.0f / H_);
    scale[m] = rsqrtf(var + EPS_) * mask[m];
  }
}

// ---------------- K2: pass 1 — per-chunk local end states -------------------
// thread = (b, chunk c, h). u[l] = hs[b,l,h]*scale[b,l]*nw[h]; x = w*x + u.
__global__ __launch_bounds__(256) void k_scan1(const float* __restrict__ hs,
                                               const float* __restrict__ nw,
                                               const float* __restrict__ scale,
                                               const float* __restrict__ wr_,
                                               const float* __restrict__ wi_,
                                               float* __restrict__ endr,
                                               float* __restrict__ endi) {
  int tid = threadIdx.x;
  int h = blockIdx.x * 256 + tid;
  int c = blockIdx.y, b = blockIdx.z;
  float wr[N_], wi[N_], xr[N_], xi[N_];
  #pragma unroll
  for (int n = 0; n < N_; n++) {
    wr[n] = wr_[n * H_ + h]; wi[n] = wi_[n * H_ + h];
    xr[n] = 0.f; xi[n] = 0.f;
  }
  float nwh = nw[h];
  __shared__ float ssc[CH_];
  int l0 = c * CH_;
  if (tid < CH_) ssc[tid] = scale[(size_t)b * L_ + l0 + tid];
  __syncthreads();
  const float* hp = hs + ((size_t)b * L_ + l0) * H_ + h;
  #pragma unroll 8
  for (int l = 0; l < CH_; l++) {
    float u = hp[(size_t)l * H_] * ssc[l] * nwh;
    #pragma unroll
    for (int n = 0; n < N_; n++) {
      float oxr = xr[n];
      xr[n] = fmaf(wr[n], oxr, fmaf(-wi[n], xi[n], u));
      xi[n] = fmaf(wr[n], xi[n], wi[n] * oxr);
    }
  }
  size_t base = (((size_t)b * NC_ + c) * N_) * H_ + h;
  #pragma unroll
  for (int n = 0; n < N_; n++) {
    endr[base + (size_t)n * H_] = xr[n];
    endi[base + (size_t)n * H_] = xi[n];
  }
}

// ---------------- K3: pass 2 — sequential carry scan over chunks ------------
// thread = (b,h); carryin[c] = state entering chunk c.
__global__ __launch_bounds__(256) void k_carry(const float* __restrict__ wpr_,
                                               const float* __restrict__ wpi_,
                                               const float* __restrict__ endr,
                                               const float* __restrict__ endi,
                                               float* __restrict__ carr,
                                               float* __restrict__ cari) {
  int idx = blockIdx.x * 256 + threadIdx.x;   // < B_*H_
  int b = idx >> 10, h = idx & (H_ - 1);
  float wpr[N_], wpi[N_], sr[N_], si[N_];
  #pragma unroll
  for (int n = 0; n < N_; n++) {
    wpr[n] = wpr_[n * H_ + h]; wpi[n] = wpi_[n * H_ + h];
    sr[n] = 0.f; si[n] = 0.f;
  }
  for (int c = 0; c < NC_; c++) {
    size_t base = (((size_t)b * NC_ + c) * N_) * H_ + h;
    #pragma unroll
    for (int n = 0; n < N_; n++) {
      carr[base + (size_t)n * H_] = sr[n];
      cari[base + (size_t)n * H_] = si[n];
      float er = endr[base + (size_t)n * H_];
      float ei = endi[base + (size_t)n * H_];
      float osr = sr[n];
      sr[n] = fmaf(wpr[n], osr,  fmaf(-wpi[n], si[n], er));
      si[n] = fmaf(wpr[n], si[n], fmaf(wpi[n], osr, ei));
    }
  }
}

// ---------------- K4: pass 3 — re-scan with carry, y=2Re(C·x)+D*u, GELU -----
__global__ __launch_bounds__(256) void k_scan2(const float* __restrict__ hs,
                                               const float* __restrict__ nw,
                                               const float* __restrict__ scale,
                                               const float* __restrict__ wr_,
                                               const float* __restrict__ wi_,
                                               const float* __restrict__ c2r_,
                                               const float* __restrict__ c2i_,
                                               const float* __restrict__ Dp,
                                               const float* __restrict__ carr,
                                               const float* __restrict__ cari,
                                               unsigned short* __restrict__ ybf) {
  int tid = threadIdx.x;
  int h = blockIdx.x * 256 + tid;
  int c = blockIdx.y, b = blockIdx.z;
  float wr[N_], wi[N_], cr[N_], ci[N_], xr[N_], xi[N_];
  size_t base = (((size_t)b * NC_ + c) * N_) * H_ + h;
  #pragma unroll
  for (int n = 0; n < N_; n++) {
    wr[n] = wr_[n * H_ + h]; wi[n] = wi_[n * H_ + h];
    cr[n] = c2r_[n * H_ + h]; ci[n] = c2i_[n * H_ + h];
    xr[n] = carr[base + (size_t)n * H_];
    xi[n] = cari[base + (size_t)n * H_];
  }
  float nwh = nw[h], Dh = Dp[h];
  __shared__ float ssc[CH_];
  int l0 = c * CH_;
  if (tid < CH_) ssc[tid] = scale[(size_t)b * L_ + l0 + tid];
  __syncthreads();
  const float* hp = hs + ((size_t)b * L_ + l0) * H_ + h;
  unsigned short* yp = ybf + ((size_t)b * L_ + l0) * H_ + h;
  #pragma unroll 4
  for (int l = 0; l < CH_; l++) {
    float u = hp[(size_t)l * H_] * ssc[l] * nwh;
    float yv = u * Dh;
    #pragma unroll
    for (int n = 0; n < N_; n++) {
      float oxr = xr[n];
      xr[n] = fmaf(wr[n], oxr, fmaf(-wi[n], xi[n], u));
      xi[n] = fmaf(wr[n], xi[n], wi[n] * oxr);
      yv = fmaf(cr[n], xr[n], yv);
      yv = fmaf(-ci[n], xi[n], yv);
    }
    // exact GELU: 0.5*y*(1+erf(y/sqrt(2)))
    float g = 0.5f * yv * (1.0f + erff(yv * 0.70710678118654752f));
    yp[(size_t)l * H_] = f2bf(g);
  }
}

// ---------------- K5: GEMM Z[m,o] = y[m,:]·W[o,:]  (bf16 MFMA, m97 recipe) --
#define BM 128
#define BN 128
#define BK 32
__global__ __launch_bounds__(256) void k_gemm(const unsigned short* __restrict__ A,
                                              const unsigned short* __restrict__ Bw,
                                              float* __restrict__ Z) {
  __shared__ __align__(16) unsigned short As[BM * BK];
  __shared__ __align__(16) unsigned short Bs[BN * BK];
  const int tid  = threadIdx.x;
  const int lane = tid & 63;
  const int wave = tid >> 6;
  const int bn = blockIdx.x * BN;
  const int bm = blockIdx.y * BM;
  const int wm = (wave >> 1) * 64;
  const int wn = (wave & 1) * 64;
  const int K = H_;
  f32x4 acc[4][4];
  #pragma unroll
  for (int mi = 0; mi < 4; mi++)
    #pragma unroll
    for (int ni = 0; ni < 4; ni++) acc[mi][ni] = (f32x4){0.f, 0.f, 0.f, 0.f};

  const int g0 = tid, g1 = 256 + tid;          // 512 x 16B chunks per 8KB tile
  const int r0 = g0 >> 2, q0 = (g0 & 3) * 8;
  const int r1 = g1 >> 2, q1 = (g1 & 3) * 8;
  const int ar = lane & 15, kq = (lane >> 4) * 8;

  for (int k0 = 0; k0 < K; k0 += BK) {
    async_copy16(A  + (size_t)(bm + r0) * K + k0 + q0, &As[g0 * 8]);
    async_copy16(A  + (size_t)(bm + r1) * K + k0 + q1, &As[g1 * 8]);
    async_copy16(Bw + (size_t)(bn + r0) * K + k0 + q0, &Bs[g0 * 8]);
    async_copy16(Bw + (size_t)(bn + r1) * K + k0 + q1, &Bs[g1 * 8]);
    __syncthreads();
    bf16x8 af[4], bf[4];
    #pragma unroll
    for (int mi = 0; mi < 4; mi++)
      af[mi] = *reinterpret_cast<const bf16x8*>(&As[(wm + mi * 16 + ar) * BK + kq]);
    #pragma unroll
    for (int ni = 0; ni < 4; ni++)
      bf[ni] = *reinterpret_cast<const bf16x8*>(&Bs[(wn + ni * 16 + ar) * BK + kq]);
    #pragma unroll
    for (int mi = 0; mi < 4; mi++)
      #pragma unroll
      for (int ni = 0; ni < 4; ni++)
        acc[mi][ni] = __builtin_amdgcn_mfma_f32_16x16x32_bf16(af[mi], bf[ni], acc[mi][ni], 0, 0, 0);
    __syncthreads();
  }
  // C/D layout: col = lane&15, row = (lane>>4)*4 + reg
  #pragma unroll
  for (int mi = 0; mi < 4; mi++)
    #pragma unroll
    for (int ni = 0; ni < 4; ni++)
      #pragma unroll
      for (int r = 0; r < 4; r++) {
        int m = bm + wm + mi * 16 + (lane >> 4) * 4 + r;
        int o = bn + wn + ni * 16 + (lane & 15);
        Z[(size_t)m * O2_ + o] = acc[mi][ni][r];
      }
}

// ---------------- K6: GLU epilogue + residual -------------------------------
__global__ __launch_bounds__(256) void k_glu(const float* __restrict__ Z,
                                             const float* __restrict__ ob,
                                             const float* __restrict__ hs,
                                             float* __restrict__ out) {
  size_t i4 = (size_t)blockIdx.x * 256 + threadIdx.x;   // over M_*H_/4
  size_t m = i4 >> 8;
  int hq = (int)(i4 & 255);
  const float4* zr = reinterpret_cast<const float4*>(Z + m * O2_);
  float4 a  = zr[hq];
  float4 bb = zr[256 + hq];
  const float4* ob4 = reinterpret_cast<const float4*>(ob);
  float4 oa = ob4[hq], obv = ob4[256 + hq];
  float4 hv = reinterpret_cast<const float4*>(hs)[i4];
  float4 r;
  r.x = hv.x + (a.x + oa.x) / (1.0f + __expf(-(bb.x + obv.x)));
  r.y = hv.y + (a.y + oa.y) / (1.0f + __expf(-(bb.y + obv.y)));
  r.z = hv.z + (a.z + oa.z) / (1.0f + __expf(-(bb.z + obv.z)));
  r.w = hv.w + (a.w + oa.w) / (1.0f + __expf(-(bb.w + obv.w)));
  reinterpret_cast<float4*>(out)[i4] = r;
}

extern "C" void kernel_launch(void* const* d_in, const int* in_sizes, int n_in,
                              void* d_out, int out_size, void* d_ws, size_t ws_size,
                              hipStream_t stream) {
  const float* hs    = (const float*)d_in[0];
  const float* mask  = (const float*)d_in[1];
  const float* nw    = (const float*)d_in[2];
  const float* ldt   = (const float*)d_in[3];
  const float* lar   = (const float*)d_in[4];
  const float* aim   = (const float*)d_in[5];
  const float* crl   = (const float*)d_in[6];
  const float* cim   = (const float*)d_in[7];
  const float* Dp    = (const float*)d_in[8];
  const float* outw  = (const float*)d_in[9];
  const float* outb  = (const float*)d_in[10];
  float* out = (float*)d_out;

  size_t off = 0;
  char* ws = (char*)d_ws;
  auto nxt = [&](size_t bytes) -> void* {
    void* p = ws + off; off += (bytes + 255) & ~(size_t)255; return p;
  };
  float* wr   = (float*)nxt(H_ * N_ * 4);
  float* wi   = (float*)nxt(H_ * N_ * 4);
  float* c2r  = (float*)nxt(H_ * N_ * 4);
  float* c2i  = (float*)nxt(H_ * N_ * 4);
  float* wpr  = (float*)nxt(H_ * N_ * 4);
  float* wpi  = (float*)nxt(H_ * N_ * 4);
  float* scale= (float*)nxt((size_t)M_ * 4);
  float* endr = (float*)nxt((size_t)B_ * NC_ * N_ * H_ * 4);
  float* endi = (float*)nxt((size_t)B_ * NC_ * N_ * H_ * 4);
  float* carr = (float*)nxt((size_t)B_ * NC_ * N_ * H_ * 4);
  float* cari = (float*)nxt((size_t)B_ * NC_ * N_ * H_ * 4);
  unsigned short* Wbf = (unsigned short*)nxt((size_t)O2_ * H_ * 2);
  unsigned short* ybf = (unsigned short*)nxt((size_t)M_ * H_ * 2);
  float* Z    = (float*)nxt((size_t)M_ * O2_ * 4);

  k_params<<<dim3(H_ * N_ / 256), dim3(256), 0, stream>>>(ldt, lar, aim, crl, cim,
                                                          wr, wi, c2r, c2i, wpr, wpi);
  k_wbf<<<dim3(O2_ * H_ / 256), dim3(256), 0, stream>>>(outw, Wbf);
  k_scale<<<dim3(M_), dim3(256), 0, stream>>>(hs, mask, scale);
  k_scan1<<<dim3(H_ / 256, NC_, B_), dim3(256), 0, stream>>>(hs, nw, scale, wr, wi, endr, endi);
  k_carry<<<dim3(B_ * H_ / 256), dim3(256), 0, stream>>>(wpr, wpi, endr, endi, carr, cari);
  k_scan2<<<dim3(H_ / 256, NC_, B_), dim3(256), 0, stream>>>(hs, nw, scale, wr, wi, c2r, c2i,
                                                             Dp, carr, cari, ybf);
  k_gemm<<<dim3(O2_ / BN, M_ / BM), dim3(256), 0, stream>>>(ybf, Wbf, Z);
  k_glu<<<dim3((size_t)M_ * H_ / 4 / 256), dim3(256), 0, stream>>>(Z, outb, hs, out);
}

// Round 2
// 386.479 us; speedup vs baseline: 1.0897x; 1.0897x over previous
//
#include <hip/hip_runtime.h>

// Problem constants (fixed by the reference)
#define B_   4
#define L_   4096
#define H_   1024
#define N_   16
#define CH_  128            // scan chunk length
#define NC_  (L_/CH_)       // 32 chunks
#define M_   (B_*L_)        // 16384 GEMM rows
#define O2_  (2*H_)         // 2048 GEMM cols (packed pairs: 2j <- W[j], 2j+1 <- W[j+1024])
#define EPS_ 1e-6f

typedef __attribute__((ext_vector_type(4))) float  f32x4;
typedef __attribute__((ext_vector_type(8))) __bf16 bf16x8;

__device__ __forceinline__ unsigned short f2bf(float x) {
  union { float f; unsigned int u; } v; v.f = x;
  unsigned int r = v.u + 0x7FFFu + ((v.u >> 16) & 1u);   // RNE
  return (unsigned short)(r >> 16);
}

__device__ __forceinline__ void async_copy16(const void* g, void* l) {
  __builtin_amdgcn_global_load_lds(
      (const __attribute__((address_space(1))) unsigned int*)g,
      (__attribute__((address_space(3))) unsigned int*)l, 16, 0, 0);
}

// ---------------- K0: fused prep — SSM params + W pack->bf16 + bias pack ----
// W pack: Wp[2j][h]=W[j][h], Wp[2j+1][h]=W[j+1024][h]  (GLU partners adjacent)
__global__ void k_prep(const float* __restrict__ log_dt,
                       const float* __restrict__ log_A_real,
                       const float* __restrict__ A_imag,
                       const float* __restrict__ C_real,
                       const float* __restrict__ C_imag,
                       const float* __restrict__ outw,
                       const float* __restrict__ outb,
                       float* __restrict__ wr,  float* __restrict__ wi,
                       float* __restrict__ c2r, float* __restrict__ c2i,
                       float* __restrict__ wpr, float* __restrict__ wpi,
                       unsigned short* __restrict__ Wbf,
                       float* __restrict__ bp) {
  int idx = blockIdx.x * 256 + threadIdx.x;      // O2_*H_ threads
  int p = idx >> 10, hh = idx & (H_ - 1);
  size_t src = (size_t)((p >> 1) + (p & 1) * H_) * H_ + hh;
  Wbf[idx] = f2bf(outw[src]);
  if (idx < O2_) bp[idx] = outb[(idx >> 1) + (idx & 1) * H_];
  if (idx < H_ * N_) {
    int h = idx / N_, n = idx % N_;
    int hn = h * N_ + n;
    float dt  = expf(log_dt[h]);
    float Ar  = -expf(log_A_real[hn]);
    float Ai  = A_imag[hn];
    float dr  = Ar * dt, di = Ai * dt;          // dtA
    float er  = expf(dr);
    float wrv = er * cosf(di), wiv = er * sinf(di);   // w = exp(dtA)
    float e1r = wrv - 1.0f, e1i = wiv;                // exp(dtA)-1
    float den = Ar * Ar + Ai * Ai;
    float qr  = (e1r * Ar + e1i * Ai) / den;          // (exp(dtA)-1)/A
    float qi  = (e1i * Ar - e1r * Ai) / den;
    float Cr  = C_real[hn], Ci = C_imag[hn];
    float cdr = Cr * qr - Ci * qi;
    float cdi = Cr * qi + Ci * qr;
    float ep  = expf((float)CH_ * dr);
    int o = n * H_ + h;                                // [n][h] (lane-coalesced)
    wr[o]  = wrv;  wi[o]  = wiv;
    c2r[o] = 2.0f * cdr; c2i[o] = 2.0f * cdi;
    wpr[o] = ep * cosf((float)CH_ * di);
    wpi[o] = ep * sinf((float)CH_ * di);
  }
}

// ---------------- K1: per-row RMSNorm scale = rsqrt(mean(h^2)+eps)*mask -----
__global__ __launch_bounds__(256) void k_scale(const float* __restrict__ hs,
                                               const float* __restrict__ mask,
                                               float* __restrict__ scale) {
  int m = blockIdx.x, tid = threadIdx.x;
  float4 v = reinterpret_cast<const float4*>(hs + (size_t)m * H_)[tid];
  float s = v.x * v.x + v.y * v.y + v.z * v.z + v.w * v.w;
  #pragma unroll
  for (int off = 32; off > 0; off >>= 1) s += __shfl_down(s, off, 64);
  __shared__ float ps[4];
  if ((tid & 63) == 0) ps[tid >> 6] = s;
  __syncthreads();
  if (tid == 0) {
    float var = (ps[0] + ps[1] + ps[2] + ps[3]) * (1.0f / H_);
    scale[m] = rsqrtf(var + EPS_) * mask[m];
  }
}

// ---------------- K2: pass 1 — per-chunk local end states -------------------
__global__ __launch_bounds__(256) void k_scan1(const float* __restrict__ hs,
                                               const float* __restrict__ nw,
                                               const float* __restrict__ scale,
                                               const float* __restrict__ wr_,
                                               const float* __restrict__ wi_,
                                               float* __restrict__ endr,
                                               float* __restrict__ endi) {
  int tid = threadIdx.x;
  int h = blockIdx.x * 256 + tid;
  int c = blockIdx.y, b = blockIdx.z;
  float wr[N_], wi[N_], xr[N_], xi[N_];
  #pragma unroll
  for (int n = 0; n < N_; n++) {
    wr[n] = wr_[n * H_ + h]; wi[n] = wi_[n * H_ + h];
    xr[n] = 0.f; xi[n] = 0.f;
  }
  float nwh = nw[h];
  __shared__ float ssc[CH_];
  int l0 = c * CH_;
  if (tid < CH_) ssc[tid] = scale[(size_t)b * L_ + l0 + tid];
  __syncthreads();
  const float* hp = hs + ((size_t)b * L_ + l0) * H_ + h;
  #pragma unroll 8
  for (int l = 0; l < CH_; l++) {
    float u = hp[(size_t)l * H_] * ssc[l] * nwh;
    #pragma unroll
    for (int n = 0; n < N_; n++) {
      float oxr = xr[n];
      xr[n] = fmaf(wr[n], oxr, fmaf(-wi[n], xi[n], u));
      xi[n] = fmaf(wr[n], xi[n], wi[n] * oxr);
    }
  }
  size_t base = (((size_t)b * NC_ + c) * N_) * H_ + h;
  #pragma unroll
  for (int n = 0; n < N_; n++) {
    endr[base + (size_t)n * H_] = xr[n];
    endi[base + (size_t)n * H_] = xi[n];
  }
}

// ---------------- K3: pass 2 — carry scan, parallel over (b,n,h) ------------
__global__ __launch_bounds__(256) void k_carry(const float* __restrict__ wpr_,
                                               const float* __restrict__ wpi_,
                                               const float* __restrict__ endr,
                                               const float* __restrict__ endi,
                                               float* __restrict__ carr,
                                               float* __restrict__ cari) {
  int idx = blockIdx.x * 256 + threadIdx.x;   // B_*N_*H_ = 65536
  int h = idx & (H_ - 1);
  int n = (idx >> 10) & (N_ - 1);
  int b = idx >> 14;
  float wprv = wpr_[n * H_ + h], wpiv = wpi_[n * H_ + h];
  float sr = 0.f, si = 0.f;
  size_t cstride = (size_t)N_ * H_;
  size_t base = ((size_t)b * NC_) * cstride + (size_t)n * H_ + h;
  for (int c = 0; c < NC_; c++, base += cstride) {
    carr[base] = sr; cari[base] = si;
    float er = endr[base], ei = endi[base];
    float osr = sr;
    sr = fmaf(wprv, osr,  fmaf(-wpiv, si, er));
    si = fmaf(wprv, si, fmaf(wpiv, osr, ei));
  }
}

// ---------------- K4: pass 3 — re-scan with carry, y=2Re(C·x)+D*u, GELU -----
__global__ __launch_bounds__(256) void k_scan2(const float* __restrict__ hs,
                                               const float* __restrict__ nw,
                                               const float* __restrict__ scale,
                                               const float* __restrict__ wr_,
                                               const float* __restrict__ wi_,
                                               const float* __restrict__ c2r_,
                                               const float* __restrict__ c2i_,
                                               const float* __restrict__ Dp,
                                               const float* __restrict__ carr,
                                               const float* __restrict__ cari,
                                               unsigned short* __restrict__ ybf) {
  int tid = threadIdx.x;
  int h = blockIdx.x * 256 + tid;
  int c = blockIdx.y, b = blockIdx.z;
  float wr[N_], wi[N_], cr[N_], ci[N_], xr[N_], xi[N_];
  size_t base = (((size_t)b * NC_ + c) * N_) * H_ + h;
  #pragma unroll
  for (int n = 0; n < N_; n++) {
    wr[n] = wr_[n * H_ + h]; wi[n] = wi_[n * H_ + h];
    cr[n] = c2r_[n * H_ + h]; ci[n] = c2i_[n * H_ + h];
    xr[n] = carr[base + (size_t)n * H_];
    xi[n] = cari[base + (size_t)n * H_];
  }
  float nwh = nw[h], Dh = Dp[h];
  __shared__ float ssc[CH_];
  int l0 = c * CH_;
  if (tid < CH_) ssc[tid] = scale[(size_t)b * L_ + l0 + tid];
  __syncthreads();
  const float* hp = hs + ((size_t)b * L_ + l0) * H_ + h;
  unsigned short* yp = ybf + ((size_t)b * L_ + l0) * H_ + h;
  #pragma unroll 4
  for (int l = 0; l < CH_; l++) {
    float u = hp[(size_t)l * H_] * ssc[l] * nwh;
    float yv = u * Dh;
    #pragma unroll
    for (int n = 0; n < N_; n++) {
      float oxr = xr[n];
      xr[n] = fmaf(wr[n], oxr, fmaf(-wi[n], xi[n], u));
      xi[n] = fmaf(wr[n], xi[n], wi[n] * oxr);
      yv = fmaf(cr[n], xr[n], yv);
      yv = fmaf(-ci[n], xi[n], yv);
    }
    // exact GELU: 0.5*y*(1+erf(y/sqrt(2)))
    float g = 0.5f * yv * (1.0f + erff(yv * 0.70710678118654752f));
    yp[(size_t)l * H_] = f2bf(g);
  }
}

// ---------------- K5: GEMM + fused GLU/bias/residual epilogue ---------------
// Zp[m,p] = y[m,:]·Wp[p,:]; GLU pairs are adjacent columns (p even = a, odd = b).
// LDS chunk swizzle ci' = ci ^ ((row>>1)&3) breaks the 8-way bank conflict of
// 64B-stride rows (global side of global_load_lds is per-lane free).
#define BM 128
#define BN 128
#define BK 32
__global__ __launch_bounds__(256) void k_gemm(const unsigned short* __restrict__ A,
                                              const unsigned short* __restrict__ Bw,
                                              const float* __restrict__ bp,
                                              const float* __restrict__ hs,
                                              float* __restrict__ out) {
  __shared__ __align__(16) unsigned short As[BM * BK];
  __shared__ __align__(16) unsigned short Bs[BN * BK];
  const int tid  = threadIdx.x;
  const int lane = tid & 63;
  const int wave = tid >> 6;
  const int bn = blockIdx.x * BN;
  const int bm = blockIdx.y * BM;
  const int wm = (wave >> 1) * 64;
  const int wn = (wave & 1) * 64;
  const int K = H_;
  f32x4 acc[4][4];
  #pragma unroll
  for (int mi = 0; mi < 4; mi++)
    #pragma unroll
    for (int ni = 0; ni < 4; ni++) acc[mi][ni] = (f32x4){0.f, 0.f, 0.f, 0.f};

  const int g0 = tid, g1 = 256 + tid;          // 512 x 16B chunks per 8KB tile
  const int r0 = g0 >> 2, c0 = ((g0 & 3) ^ ((r0 >> 1) & 3)) * 8;
  const int r1 = g1 >> 2, c1 = ((g1 & 3) ^ ((r1 >> 1) & 3)) * 8;
  const int ar = lane & 15, kqi = lane >> 4;   // reader chunk index 0..3

  for (int k0 = 0; k0 < K; k0 += BK) {
    async_copy16(A  + (size_t)(bm + r0) * K + k0 + c0, &As[g0 * 8]);
    async_copy16(A  + (size_t)(bm + r1) * K + k0 + c1, &As[g1 * 8]);
    async_copy16(Bw + (size_t)(bn + r0) * K + k0 + c0, &Bs[g0 * 8]);
    async_copy16(Bw + (size_t)(bn + r1) * K + k0 + c1, &Bs[g1 * 8]);
    __syncthreads();
    bf16x8 af[4], bf[4];
    #pragma unroll
    for (int mi = 0; mi < 4; mi++) {
      int row = wm + mi * 16 + ar;
      af[mi] = *reinterpret_cast<const bf16x8*>(&As[row * BK + ((kqi ^ ((row >> 1) & 3)) * 8)]);
    }
    #pragma unroll
    for (int ni = 0; ni < 4; ni++) {
      int row = wn + ni * 16 + ar;
      bf[ni] = *reinterpret_cast<const bf16x8*>(&Bs[row * BK + ((kqi ^ ((row >> 1) & 3)) * 8)]);
    }
    #pragma unroll
    for (int mi = 0; mi < 4; mi++)
      #pragma unroll
      for (int ni = 0; ni < 4; ni++)
        acc[mi][ni] = __builtin_amdgcn_mfma_f32_16x16x32_bf16(af[mi], bf[ni], acc[mi][ni], 0, 0, 0);
    __syncthreads();
  }
  // C/D layout: col = lane&15, row = (lane>>4)*4 + reg.
  // Even col p = GLU 'a' (gate j=p/2), odd col p+1 = GLU 'b' — in lane^1, same row.
  #pragma unroll
  for (int mi = 0; mi < 4; mi++) {
    int mrow0 = bm + wm + mi * 16 + (lane >> 4) * 4;
    #pragma unroll
    for (int ni = 0; ni < 4; ni++) {
      int p  = bn + wn + ni * 16 + (lane & 15);
      int pe = p & ~1;
      float bA = bp[pe], bB = bp[pe + 1];
      int j = pe >> 1;
      #pragma unroll
      for (int r = 0; r < 4; r++) {
        float v = acc[mi][ni][r];
        float w = __shfl_xor(v, 1, 64);        // partner column's value
        if (!(lane & 1)) {
          float g = (v + bA) / (1.0f + __expf(-(w + bB)));
          size_t o = (size_t)(mrow0 + r) * H_ + j;
          out[o] = hs[o] + g;
        }
      }
    }
  }
}

extern "C" void kernel_launch(void* const* d_in, const int* in_sizes, int n_in,
                              void* d_out, int out_size, void* d_ws, size_t ws_size,
                              hipStream_t stream) {
  const float* hs    = (const float*)d_in[0];
  const float* mask  = (const float*)d_in[1];
  const float* nw    = (const float*)d_in[2];
  const float* ldt   = (const float*)d_in[3];
  const float* lar   = (const float*)d_in[4];
  const float* aim   = (const float*)d_in[5];
  const float* crl   = (const float*)d_in[6];
  const float* cim   = (const float*)d_in[7];
  const float* Dp    = (const float*)d_in[8];
  const float* outw  = (const float*)d_in[9];
  const float* outb  = (const float*)d_in[10];
  float* out = (float*)d_out;

  size_t off = 0;
  char* ws = (char*)d_ws;
  auto nxt = [&](size_t bytes) -> void* {
    void* p = ws + off; off += (bytes + 255) & ~(size_t)255; return p;
  };
  float* wr   = (float*)nxt(H_ * N_ * 4);
  float* wi   = (float*)nxt(H_ * N_ * 4);
  float* c2r  = (float*)nxt(H_ * N_ * 4);
  float* c2i  = (float*)nxt(H_ * N_ * 4);
  float* wpr  = (float*)nxt(H_ * N_ * 4);
  float* wpi  = (float*)nxt(H_ * N_ * 4);
  float* bpck = (float*)nxt(O2_ * 4);
  float* scale= (float*)nxt((size_t)M_ * 4);
  float* endr = (float*)nxt((size_t)B_ * NC_ * N_ * H_ * 4);
  float* endi = (float*)nxt((size_t)B_ * NC_ * N_ * H_ * 4);
  float* carr = (float*)nxt((size_t)B_ * NC_ * N_ * H_ * 4);
  float* cari = (float*)nxt((size_t)B_ * NC_ * N_ * H_ * 4);
  unsigned short* Wbf = (unsigned short*)nxt((size_t)O2_ * H_ * 2);
  unsigned short* ybf = (unsigned short*)nxt((size_t)M_ * H_ * 2);

  k_prep<<<dim3(O2_ * H_ / 256), dim3(256), 0, stream>>>(ldt, lar, aim, crl, cim,
                                                         outw, outb,
                                                         wr, wi, c2r, c2i, wpr, wpi,
                                                         Wbf, bpck);
  k_scale<<<dim3(M_), dim3(256), 0, stream>>>(hs, mask, scale);
  k_scan1<<<dim3(H_ / 256, NC_, B_), dim3(256), 0, stream>>>(hs, nw, scale, wr, wi, endr, endi);
  k_carry<<<dim3(B_ * N_ * H_ / 256), dim3(256), 0, stream>>>(wpr, wpi, endr, endi, carr, cari);
  k_scan2<<<dim3(H_ / 256, NC_, B_), dim3(256), 0, stream>>>(hs, nw, scale, wr, wi, c2r, c2i,
                                                             Dp, carr, cari, ybf);
  k_gemm<<<dim3(O2_ / BN, M_ / BM), dim3(256), 0, stream>>>(ybf, Wbf, bpck, hs, out);
}

// Round 3
// 366.900 us; speedup vs baseline: 1.1479x; 1.0534x over previous
//
#include <hip/hip_runtime.h>

// Problem constants (fixed by the reference)
#define B_   4
#define L_   4096
#define H_   1024
#define N_   16
#define CH_  64             // scan chunk length
#define NC_  (L_/CH_)       // 64 chunks
#define M_   (B_*L_)        // 16384 GEMM rows
#define O2_  (2*H_)         // 2048 GEMM cols (packed pairs: 2j <- W[j], 2j+1 <- W[j+1024])
#define EPS_ 1e-6f

typedef __attribute__((ext_vector_type(4))) float  f32x4;
typedef __attribute__((ext_vector_type(8))) __bf16 bf16x8;

__device__ __forceinline__ unsigned short f2bf(float x) {
  union { float f; unsigned int u; } v; v.f = x;
  unsigned int r = v.u + 0x7FFFu + ((v.u >> 16) & 1u);   // RNE
  return (unsigned short)(r >> 16);
}
__device__ __forceinline__ float bf2f(unsigned short x) {
  union { unsigned int u; float f; } v; v.u = ((unsigned int)x) << 16;
  return v.f;
}

__device__ __forceinline__ void async_copy16(const void* g, void* l) {
  __builtin_amdgcn_global_load_lds(
      (const __attribute__((address_space(1))) unsigned int*)g,
      (__attribute__((address_space(3))) unsigned int*)l, 16, 0, 0);
}

// ---------------- K0: fused prep — SSM params + W pack->bf16 + bias pack ----
// W pack: Wp[2j][h]=W[j][h], Wp[2j+1][h]=W[j+1024][h]  (GLU partners adjacent)
__global__ void k_prep(const float* __restrict__ log_dt,
                       const float* __restrict__ log_A_real,
                       const float* __restrict__ A_imag,
                       const float* __restrict__ C_real,
                       const float* __restrict__ C_imag,
                       const float* __restrict__ outw,
                       const float* __restrict__ outb,
                       float* __restrict__ wr,  float* __restrict__ wi,
                       float* __restrict__ c2r, float* __restrict__ c2i,
                       float* __restrict__ wpr, float* __restrict__ wpi,
                       unsigned short* __restrict__ Wbf,
                       float* __restrict__ bp) {
  int idx = blockIdx.x * 256 + threadIdx.x;      // O2_*H_ threads
  int p = idx >> 10, hh = idx & (H_ - 1);
  size_t src = (size_t)((p >> 1) + (p & 1) * H_) * H_ + hh;
  Wbf[idx] = f2bf(outw[src]);
  if (idx < O2_) bp[idx] = outb[(idx >> 1) + (idx & 1) * H_];
  if (idx < H_ * N_) {
    int h = idx / N_, n = idx % N_;
    int hn = h * N_ + n;
    float dt  = expf(log_dt[h]);
    float Ar  = -expf(log_A_real[hn]);
    float Ai  = A_imag[hn];
    float dr  = Ar * dt, di = Ai * dt;          // dtA
    float er  = expf(dr);
    float wrv = er * cosf(di), wiv = er * sinf(di);   // w = exp(dtA)
    float e1r = wrv - 1.0f, e1i = wiv;                // exp(dtA)-1
    float den = Ar * Ar + Ai * Ai;
    float qr  = (e1r * Ar + e1i * Ai) / den;          // (exp(dtA)-1)/A
    float qi  = (e1i * Ar - e1r * Ai) / den;
    float Cr  = C_real[hn], Ci = C_imag[hn];
    float cdr = Cr * qr - Ci * qi;
    float cdi = Cr * qi + Ci * qr;
    float ep  = expf((float)CH_ * dr);
    int o = n * H_ + h;                                // [n][h] (lane-coalesced)
    wr[o]  = wrv;  wi[o]  = wiv;
    c2r[o] = 2.0f * cdr; c2i[o] = 2.0f * cdi;
    wpr[o] = ep * cosf((float)CH_ * di);
    wpi[o] = ep * sinf((float)CH_ * di);
  }
}

// ---------------- K1: per-row RMSNorm scale = rsqrt(mean(h^2)+eps)*mask -----
__global__ __launch_bounds__(256) void k_scale(const float* __restrict__ hs,
                                               const float* __restrict__ mask,
                                               float* __restrict__ scale) {
  int m = blockIdx.x, tid = threadIdx.x;
  float4 v = reinterpret_cast<const float4*>(hs + (size_t)m * H_)[tid];
  float s = v.x * v.x + v.y * v.y + v.z * v.z + v.w * v.w;
  #pragma unroll
  for (int off = 32; off > 0; off >>= 1) s += __shfl_down(s, off, 64);
  __shared__ float ps[4];
  if ((tid & 63) == 0) ps[tid >> 6] = s;
  __syncthreads();
  if (tid == 0) {
    float var = (ps[0] + ps[1] + ps[2] + ps[3]) * (1.0f / H_);
    scale[m] = rsqrtf(var + EPS_) * mask[m];
  }
}

// ---------------- K2: pass 1 — local end states + u (bf16) ------------------
__global__ __launch_bounds__(256) void k_scan1(const float* __restrict__ hs,
                                               const float* __restrict__ nw,
                                               const float* __restrict__ scale,
                                               const float* __restrict__ wr_,
                                               const float* __restrict__ wi_,
                                               float* __restrict__ endr,
                                               float* __restrict__ endi,
                                               unsigned short* __restrict__ ubf) {
  int tid = threadIdx.x;
  int h = blockIdx.x * 256 + tid;
  int c = blockIdx.y, b = blockIdx.z;
  float wr[N_], wi[N_], xr[N_], xi[N_];
  #pragma unroll
  for (int n = 0; n < N_; n++) {
    wr[n] = wr_[n * H_ + h]; wi[n] = wi_[n * H_ + h];
    xr[n] = 0.f; xi[n] = 0.f;
  }
  float nwh = nw[h];
  __shared__ float ssc[CH_];
  int l0 = c * CH_;
  if (tid < CH_) ssc[tid] = scale[(size_t)b * L_ + l0 + tid];
  __syncthreads();
  const float* hp = hs + ((size_t)b * L_ + l0) * H_ + h;
  unsigned short* up = ubf + ((size_t)b * L_ + l0) * H_ + h;
  #pragma unroll 8
  for (int l = 0; l < CH_; l++) {
    float u = hp[(size_t)l * H_] * ssc[l] * nwh;
    unsigned short ub = f2bf(u);
    up[(size_t)l * H_] = ub;
    u = bf2f(ub);                 // keep scan consistent with stored u
    #pragma unroll
    for (int n = 0; n < N_; n++) {
      float oxr = xr[n];
      xr[n] = fmaf(wr[n], oxr, fmaf(-wi[n], xi[n], u));
      xi[n] = fmaf(wr[n], xi[n], wi[n] * oxr);
    }
  }
  size_t base = (((size_t)b * NC_ + c) * N_) * H_ + h;
  #pragma unroll
  for (int n = 0; n < N_; n++) {
    endr[base + (size_t)n * H_] = xr[n];
    endi[base + (size_t)n * H_] = xi[n];
  }
}

// ---------------- K3: pass 2 — carry scan, parallel over (b,n,h) ------------
__global__ __launch_bounds__(256) void k_carry(const float* __restrict__ wpr_,
                                               const float* __restrict__ wpi_,
                                               const float* __restrict__ endr,
                                               const float* __restrict__ endi,
                                               float* __restrict__ carr,
                                               float* __restrict__ cari) {
  int idx = blockIdx.x * 256 + threadIdx.x;   // B_*N_*H_ = 65536
  int h = idx & (H_ - 1);
  int n = (idx >> 10) & (N_ - 1);
  int b = idx >> 14;
  float wprv = wpr_[n * H_ + h], wpiv = wpi_[n * H_ + h];
  float sr = 0.f, si = 0.f;
  size_t cstride = (size_t)N_ * H_;
  size_t base = ((size_t)b * NC_) * cstride + (size_t)n * H_ + h;
  for (int c = 0; c < NC_; c++, base += cstride) {
    carr[base] = sr; cari[base] = si;
    float er = endr[base], ei = endi[base];
    float osr = sr;
    sr = fmaf(wprv, osr,  fmaf(-wpiv, si, er));
    si = fmaf(wprv, si, fmaf(wpiv, osr, ei));
  }
}

// ---------------- K4: pass 3 — re-scan u with carry, y=2Re(C·x)+D*u, GELU ---
__global__ __launch_bounds__(256) void k_scan2(const unsigned short* __restrict__ ubf,
                                               const float* __restrict__ wr_,
                                               const float* __restrict__ wi_,
                                               const float* __restrict__ c2r_,
                                               const float* __restrict__ c2i_,
                                               const float* __restrict__ Dp,
                                               const float* __restrict__ carr,
                                               const float* __restrict__ cari,
                                               unsigned short* __restrict__ ybf) {
  int tid = threadIdx.x;
  int h = blockIdx.x * 256 + tid;
  int c = blockIdx.y, b = blockIdx.z;
  float wr[N_], wi[N_], cr[N_], ci[N_], xr[N_], xi[N_];
  size_t base = (((size_t)b * NC_ + c) * N_) * H_ + h;
  #pragma unroll
  for (int n = 0; n < N_; n++) {
    wr[n] = wr_[n * H_ + h]; wi[n] = wi_[n * H_ + h];
    cr[n] = c2r_[n * H_ + h]; ci[n] = c2i_[n * H_ + h];
    xr[n] = carr[base + (size_t)n * H_];
    xi[n] = cari[base + (size_t)n * H_];
  }
  float Dh = Dp[h];
  int l0 = c * CH_;
  const unsigned short* up = ubf + ((size_t)b * L_ + l0) * H_ + h;
  unsigned short* yp = ybf + ((size_t)b * L_ + l0) * H_ + h;
  #pragma unroll 8
  for (int l = 0; l < CH_; l++) {
    float u = bf2f(up[(size_t)l * H_]);
    float yv = u * Dh;
    #pragma unroll
    for (int n = 0; n < N_; n++) {
      float oxr = xr[n];
      xr[n] = fmaf(wr[n], oxr, fmaf(-wi[n], xi[n], u));
      xi[n] = fmaf(wr[n], xi[n], wi[n] * oxr);
      yv = fmaf(cr[n], xr[n], yv);
      yv = fmaf(-ci[n], xi[n], yv);
    }
    // exact GELU: 0.5*y*(1+erf(y/sqrt(2)))
    float g = 0.5f * yv * (1.0f + erff(yv * 0.70710678118654752f));
    yp[(size_t)l * H_] = f2bf(g);
  }
}

// ---------------- K5: GEMM + fused GLU/bias/residual epilogue ---------------
// Zp[m,p] = y[m,:]·Wp[p,:]; GLU pairs are adjacent columns (p even = a, odd = b).
// LDS chunk swizzle ci' = ci ^ ((row>>1)&3) breaks the 8-way bank conflict of
// 64B-stride rows. Epilogue stages the 128x64 g-tile in LDS (reusing the
// staging LDS) so hs/out traffic is float4-coalesced (256B segments).
#define BM 128
#define BN 128
#define BK 32
#define GSTRIDE 68          // fp32 row stride of g-tile (pad, 16B-aligned)
__global__ __launch_bounds__(256) void k_gemm(const unsigned short* __restrict__ A,
                                              const unsigned short* __restrict__ Bw,
                                              const float* __restrict__ bp,
                                              const float* __restrict__ hs,
                                              float* __restrict__ out) {
  __shared__ __align__(16) char smem[BM * GSTRIDE * 4];   // 34816 B (>16KB staging)
  unsigned short* As = (unsigned short*)smem;             // BM*BK
  unsigned short* Bs = As + BM * BK;                      // BN*BK
  float* gt = (float*)smem;                               // 128 x GSTRIDE fp32
  const int tid  = threadIdx.x;
  const int lane = tid & 63;
  const int wave = tid >> 6;
  const int bn = blockIdx.x * BN;
  const int bm = blockIdx.y * BM;
  const int wm = (wave >> 1) * 64;
  const int wn = (wave & 1) * 64;
  const int K = H_;
  f32x4 acc[4][4];
  #pragma unroll
  for (int mi = 0; mi < 4; mi++)
    #pragma unroll
    for (int ni = 0; ni < 4; ni++) acc[mi][ni] = (f32x4){0.f, 0.f, 0.f, 0.f};

  const int g0 = tid, g1 = 256 + tid;          // 512 x 16B chunks per 8KB tile
  const int r0 = g0 >> 2, c0 = ((g0 & 3) ^ ((r0 >> 1) & 3)) * 8;
  const int r1 = g1 >> 2, c1 = ((g1 & 3) ^ ((r1 >> 1) & 3)) * 8;
  const int ar = lane & 15, kqi = lane >> 4;   // reader chunk index 0..3

  for (int k0 = 0; k0 < K; k0 += BK) {
    async_copy16(A  + (size_t)(bm + r0) * K + k0 + c0, &As[g0 * 8]);
    async_copy16(A  + (size_t)(bm + r1) * K + k0 + c1, &As[g1 * 8]);
    async_copy16(Bw + (size_t)(bn + r0) * K + k0 + c0, &Bs[g0 * 8]);
    async_copy16(Bw + (size_t)(bn + r1) * K + k0 + c1, &Bs[g1 * 8]);
    __syncthreads();
    bf16x8 af[4], bf[4];
    #pragma unroll
    for (int mi = 0; mi < 4; mi++) {
      int row = wm + mi * 16 + ar;
      af[mi] = *reinterpret_cast<const bf16x8*>(&As[row * BK + ((kqi ^ ((row >> 1) & 3)) * 8)]);
    }
    #pragma unroll
    for (int ni = 0; ni < 4; ni++) {
      int row = wn + ni * 16 + ar;
      bf[ni] = *reinterpret_cast<const bf16x8*>(&Bs[row * BK + ((kqi ^ ((row >> 1) & 3)) * 8)]);
    }
    #pragma unroll
    for (int mi = 0; mi < 4; mi++)
      #pragma unroll
      for (int ni = 0; ni < 4; ni++)
        acc[mi][ni] = __builtin_amdgcn_mfma_f32_16x16x32_bf16(af[mi], bf[ni], acc[mi][ni], 0, 0, 0);
    __syncthreads();
  }
  // C/D layout: col = lane&15, row = (lane>>4)*4 + reg.
  // Even col p = GLU 'a' (gate j=p/2), odd col p+1 = GLU 'b' — in lane^1, same row.
  #pragma unroll
  for (int ni = 0; ni < 4; ni++) {
    int p  = wn + ni * 16 + (lane & 15);     // local packed col
    int pe = (bn + p) & ~1;
    float bA = bp[pe], bB = bp[pe + 1];
    int jl = p >> 1;                         // local output col (0..63)
    #pragma unroll
    for (int mi = 0; mi < 4; mi++) {
      int row0 = wm + mi * 16 + (lane >> 4) * 4;
      #pragma unroll
      for (int r = 0; r < 4; r++) {
        float v = acc[mi][ni][r];
        float w = __shfl_xor(v, 1, 64);      // partner column's value
        if (!(lane & 1))
          gt[(row0 + r) * GSTRIDE + jl] = (v + bA) / (1.0f + __expf(-(w + bB)));
      }
    }
  }
  __syncthreads();
  {
    int c4 = tid & 15;                       // float4 column within 64
    int rr = tid >> 4;                       // 0..15
    size_t obase = (size_t)bm * H_ + (bn >> 1);
    #pragma unroll
    for (int rep = 0; rep < 8; rep++) {
      int row = rep * 16 + rr;
      float4 g = *reinterpret_cast<const float4*>(&gt[row * GSTRIDE + c4 * 4]);
      size_t o = obase + (size_t)row * H_ + c4 * 4;
      float4 hv = *reinterpret_cast<const float4*>(&hs[o]);
      float4 rv = {hv.x + g.x, hv.y + g.y, hv.z + g.z, hv.w + g.w};
      *reinterpret_cast<float4*>(&out[o]) = rv;
    }
  }
}

extern "C" void kernel_launch(void* const* d_in, const int* in_sizes, int n_in,
                              void* d_out, int out_size, void* d_ws, size_t ws_size,
                              hipStream_t stream) {
  const float* hs    = (const float*)d_in[0];
  const float* mask  = (const float*)d_in[1];
  const float* nw    = (const float*)d_in[2];
  const float* ldt   = (const float*)d_in[3];
  const float* lar   = (const float*)d_in[4];
  const float* aim   = (const float*)d_in[5];
  const float* crl   = (const float*)d_in[6];
  const float* cim   = (const float*)d_in[7];
  const float* Dp    = (const float*)d_in[8];
  const float* outw  = (const float*)d_in[9];
  const float* outb  = (const float*)d_in[10];
  float* out = (float*)d_out;

  size_t off = 0;
  char* ws = (char*)d_ws;
  auto nxt = [&](size_t bytes) -> void* {
    void* p = ws + off; off += (bytes + 255) & ~(size_t)255; return p;
  };
  float* wr   = (float*)nxt(H_ * N_ * 4);
  float* wi   = (float*)nxt(H_ * N_ * 4);
  float* c2r  = (float*)nxt(H_ * N_ * 4);
  float* c2i  = (float*)nxt(H_ * N_ * 4);
  float* wpr  = (float*)nxt(H_ * N_ * 4);
  float* wpi  = (float*)nxt(H_ * N_ * 4);
  float* bpck = (float*)nxt(O2_ * 4);
  float* scale= (float*)nxt((size_t)M_ * 4);
  float* endr = (float*)nxt((size_t)B_ * NC_ * N_ * H_ * 4);
  float* endi = (float*)nxt((size_t)B_ * NC_ * N_ * H_ * 4);
  float* carr = (float*)nxt((size_t)B_ * NC_ * N_ * H_ * 4);
  float* cari = (float*)nxt((size_t)B_ * NC_ * N_ * H_ * 4);
  unsigned short* Wbf = (unsigned short*)nxt((size_t)O2_ * H_ * 2);
  unsigned short* ubf = (unsigned short*)nxt((size_t)M_ * H_ * 2);
  unsigned short* ybf = (unsigned short*)nxt((size_t)M_ * H_ * 2);

  k_prep<<<dim3(O2_ * H_ / 256), dim3(256), 0, stream>>>(ldt, lar, aim, crl, cim,
                                                         outw, outb,
                                                         wr, wi, c2r, c2i, wpr, wpi,
                                                         Wbf, bpck);
  k_scale<<<dim3(M_), dim3(256), 0, stream>>>(hs, mask, scale);
  k_scan1<<<dim3(H_ / 256, NC_, B_), dim3(256), 0, stream>>>(hs, nw, scale, wr, wi,
                                                             endr, endi, ubf);
  k_carry<<<dim3(B_ * N_ * H_ / 256), dim3(256), 0, stream>>>(wpr, wpi, endr, endi, carr, cari);
  k_scan2<<<dim3(H_ / 256, NC_, B_), dim3(256), 0, stream>>>(ubf, wr, wi, c2r, c2i,
                                                             Dp, carr, cari, ybf);
  k_gemm<<<dim3(O2_ / BN, M_ / BM), dim3(256), 0, stream>>>(ybf, Wbf, bpck, hs, out);
}

// Round 4
// 363.128 us; speedup vs baseline: 1.1598x; 1.0104x over previous
//
#include <hip/hip_runtime.h>

// Problem constants (fixed by the reference)
#define B_   4
#define L_   4096
#define H_   1024
#define N_   16
#define CH_  64             // scan chunk length
#define NC_  (L_/CH_)       // 64 chunks
#define M_   (B_*L_)        // 16384 GEMM rows
#define O2_  (2*H_)         // 2048 GEMM cols (packed pairs: 2j <- W[j], 2j+1 <- W[j+1024])
#define EPS_ 1e-6f

typedef __attribute__((ext_vector_type(4))) float  f32x4;
typedef __attribute__((ext_vector_type(8))) __bf16 bf16x8;

__device__ __forceinline__ unsigned short f2bf(float x) {
  union { float f; unsigned int u; } v; v.f = x;
  unsigned int r = v.u + 0x7FFFu + ((v.u >> 16) & 1u);   // RNE
  return (unsigned short)(r >> 16);
}
__device__ __forceinline__ float bf2f(unsigned short x) {
  union { unsigned int u; float f; } v; v.u = ((unsigned int)x) << 16;
  return v.f;
}

__device__ __forceinline__ void async_copy16(const void* g, void* l) {
  __builtin_amdgcn_global_load_lds(
      (const __attribute__((address_space(1))) unsigned int*)g,
      (__attribute__((address_space(3))) unsigned int*)l, 16, 0, 0);
}

// ---------------- K0: fused prep — SSM params + W pack->bf16 + bias pack ----
// W pack: Wp[2j][h]=W[j][h], Wp[2j+1][h]=W[j+1024][h]  (GLU partners adjacent)
__global__ void k_prep(const float* __restrict__ log_dt,
                       const float* __restrict__ log_A_real,
                       const float* __restrict__ A_imag,
                       const float* __restrict__ C_real,
                       const float* __restrict__ C_imag,
                       const float* __restrict__ outw,
                       const float* __restrict__ outb,
                       float* __restrict__ wr,  float* __restrict__ wi,
                       float* __restrict__ c2r, float* __restrict__ c2i,
                       float* __restrict__ wpr, float* __restrict__ wpi,
                       unsigned short* __restrict__ Wbf,
                       float* __restrict__ bp) {
  int idx = blockIdx.x * 256 + threadIdx.x;      // O2_*H_ threads
  int p = idx >> 10, hh = idx & (H_ - 1);
  size_t src = (size_t)((p >> 1) + (p & 1) * H_) * H_ + hh;
  Wbf[idx] = f2bf(outw[src]);
  if (idx < O2_) bp[idx] = outb[(idx >> 1) + (idx & 1) * H_];
  if (idx < H_ * N_) {
    int h = idx / N_, n = idx % N_;
    int hn = h * N_ + n;
    float dt  = expf(log_dt[h]);
    float Ar  = -expf(log_A_real[hn]);
    float Ai  = A_imag[hn];
    float dr  = Ar * dt, di = Ai * dt;          // dtA
    float er  = expf(dr);
    float wrv = er * cosf(di), wiv = er * sinf(di);   // w = exp(dtA)
    float e1r = wrv - 1.0f, e1i = wiv;                // exp(dtA)-1
    float den = Ar * Ar + Ai * Ai;
    float qr  = (e1r * Ar + e1i * Ai) / den;          // (exp(dtA)-1)/A
    float qi  = (e1i * Ar - e1r * Ai) / den;
    float Cr  = C_real[hn], Ci = C_imag[hn];
    float cdr = Cr * qr - Ci * qi;
    float cdi = Cr * qi + Ci * qr;
    float ep  = expf((float)CH_ * dr);
    int o = n * H_ + h;                                // [n][h] (lane-coalesced)
    wr[o]  = wrv;  wi[o]  = wiv;
    c2r[o] = 2.0f * cdr; c2i[o] = 2.0f * cdi;
    wpr[o] = ep * cosf((float)CH_ * di);
    wpi[o] = ep * sinf((float)CH_ * di);
  }
}

// ---------------- K1: per-row RMSNorm scale = rsqrt(mean(h^2)+eps)*mask -----
__global__ __launch_bounds__(256) void k_scale(const float* __restrict__ hs,
                                               const float* __restrict__ mask,
                                               float* __restrict__ scale) {
  int m = blockIdx.x, tid = threadIdx.x;
  float4 v = reinterpret_cast<const float4*>(hs + (size_t)m * H_)[tid];
  float s = v.x * v.x + v.y * v.y + v.z * v.z + v.w * v.w;
  #pragma unroll
  for (int off = 32; off > 0; off >>= 1) s += __shfl_down(s, off, 64);
  __shared__ float ps[4];
  if ((tid & 63) == 0) ps[tid >> 6] = s;
  __syncthreads();
  if (tid == 0) {
    float var = (ps[0] + ps[1] + ps[2] + ps[3]) * (1.0f / H_);
    scale[m] = rsqrtf(var + EPS_) * mask[m];
  }
}

// ---------------- K2: pass 1 — local end states + u (bf16) ------------------
__global__ __launch_bounds__(256) void k_scan1(const float* __restrict__ hs,
                                               const float* __restrict__ nw,
                                               const float* __restrict__ scale,
                                               const float* __restrict__ wr_,
                                               const float* __restrict__ wi_,
                                               float* __restrict__ endr,
                                               float* __restrict__ endi,
                                               unsigned short* __restrict__ ubf) {
  int tid = threadIdx.x;
  int h = blockIdx.x * 256 + tid;
  int c = blockIdx.y, b = blockIdx.z;
  float wr[N_], wi[N_], xr[N_], xi[N_];
  #pragma unroll
  for (int n = 0; n < N_; n++) {
    wr[n] = wr_[n * H_ + h]; wi[n] = wi_[n * H_ + h];
    xr[n] = 0.f; xi[n] = 0.f;
  }
  float nwh = nw[h];
  int l0 = c * CH_;
  const float* scp = scale + (size_t)b * L_ + l0;   // block-uniform per l
  const float* hp = hs + ((size_t)b * L_ + l0) * H_ + h;
  unsigned short* up = ubf + ((size_t)b * L_ + l0) * H_ + h;
  #pragma unroll 8
  for (int l = 0; l < CH_; l++) {
    float u = hp[(size_t)l * H_] * scp[l] * nwh;
    unsigned short ub = f2bf(u);
    up[(size_t)l * H_] = ub;
    u = bf2f(ub);                 // keep scan consistent with stored u
    #pragma unroll
    for (int n = 0; n < N_; n++) {
      float oxr = xr[n];
      xr[n] = fmaf(wr[n], oxr, fmaf(-wi[n], xi[n], u));
      xi[n] = fmaf(wr[n], xi[n], wi[n] * oxr);
    }
  }
  size_t base = (((size_t)b * NC_ + c) * N_) * H_ + h;
  #pragma unroll
  for (int n = 0; n < N_; n++) {
    endr[base + (size_t)n * H_] = xr[n];
    endi[base + (size_t)n * H_] = xi[n];
  }
}

// ---------------- K3: pass 2 — carry scan, parallel over (b,n,h) ------------
__global__ __launch_bounds__(256) void k_carry(const float* __restrict__ wpr_,
                                               const float* __restrict__ wpi_,
                                               const float* __restrict__ endr,
                                               const float* __restrict__ endi,
                                               float* __restrict__ carr,
                                               float* __restrict__ cari) {
  int idx = blockIdx.x * 256 + threadIdx.x;   // B_*N_*H_ = 65536
  int h = idx & (H_ - 1);
  int n = (idx >> 10) & (N_ - 1);
  int b = idx >> 14;
  float wprv = wpr_[n * H_ + h], wpiv = wpi_[n * H_ + h];
  float sr = 0.f, si = 0.f;
  size_t cstride = (size_t)N_ * H_;
  size_t base = ((size_t)b * NC_) * cstride + (size_t)n * H_ + h;
  for (int c = 0; c < NC_; c++, base += cstride) {
    carr[base] = sr; cari[base] = si;
    float er = endr[base], ei = endi[base];
    float osr = sr;
    sr = fmaf(wprv, osr,  fmaf(-wpiv, si, er));
    si = fmaf(wprv, si, fmaf(wpiv, osr, ei));
  }
}

// ---------------- K4: pass 3 — re-scan u with carry, y=2Re(C·x)+D*u, GELU ---
__global__ __launch_bounds__(256) void k_scan2(const unsigned short* __restrict__ ubf,
                                               const float* __restrict__ wr_,
                                               const float* __restrict__ wi_,
                                               const float* __restrict__ c2r_,
                                               const float* __restrict__ c2i_,
                                               const float* __restrict__ Dp,
                                               const float* __restrict__ carr,
                                               const float* __restrict__ cari,
                                               unsigned short* __restrict__ ybf) {
  int tid = threadIdx.x;
  int h = blockIdx.x * 256 + tid;
  int c = blockIdx.y, b = blockIdx.z;
  float wr[N_], wi[N_], cr[N_], ci[N_], xr[N_], xi[N_];
  size_t base = (((size_t)b * NC_ + c) * N_) * H_ + h;
  #pragma unroll
  for (int n = 0; n < N_; n++) {
    wr[n] = wr_[n * H_ + h]; wi[n] = wi_[n * H_ + h];
    cr[n] = c2r_[n * H_ + h]; ci[n] = c2i_[n * H_ + h];
    xr[n] = carr[base + (size_t)n * H_];
    xi[n] = cari[base + (size_t)n * H_];
  }
  float Dh = Dp[h];
  int l0 = c * CH_;
  const unsigned short* up = ubf + ((size_t)b * L_ + l0) * H_ + h;
  unsigned short* yp = ybf + ((size_t)b * L_ + l0) * H_ + h;
  #pragma unroll 8
  for (int l = 0; l < CH_; l++) {
    float u = bf2f(up[(size_t)l * H_]);
    float yv = u * Dh;
    #pragma unroll
    for (int n = 0; n < N_; n++) {
      float oxr = xr[n];
      xr[n] = fmaf(wr[n], oxr, fmaf(-wi[n], xi[n], u));
      xi[n] = fmaf(wr[n], xi[n], wi[n] * oxr);
      yv = fmaf(cr[n], xr[n], yv);
      yv = fmaf(-ci[n], xi[n], yv);
    }
    // exact GELU: 0.5*y*(1+erf(y/sqrt(2)))
    float g = 0.5f * yv * (1.0f + erff(yv * 0.70710678118654752f));
    yp[(size_t)l * H_] = f2bf(g);
  }
}

// ---------------- K5: GEMM + fused GLU/bias/residual epilogue ---------------
// Zp[m,p] = y[m,:]·Wp[p,:]; GLU pairs are adjacent columns (p even = a, odd = b).
// BK=64: 32KB staging per iter (fits in the 34.8KB epilogue footprint), 16
// K-iterations -> half the barrier drains of BK=32. LDS swizzle: physical
// chunk g&7 of row r holds logical chunk (g&7)^(r&7); fragment reads use
// (kh*4+kqi)^(r&7) -> 2-way bank aliasing (free).
#define BM 128
#define BN 128
#define BKG 64
#define GSTRIDE 68          // fp32 row stride of g-tile (pad, 16B-aligned)
__global__ __launch_bounds__(256) void k_gemm(const unsigned short* __restrict__ A,
                                              const unsigned short* __restrict__ Bw,
                                              const float* __restrict__ bp,
                                              const float* __restrict__ hs,
                                              float* __restrict__ out) {
  __shared__ __align__(16) char smem[BM * GSTRIDE * 4];   // 34816 B
  unsigned short* As = (unsigned short*)smem;             // BM*BKG = 16KB
  unsigned short* Bs = As + BM * BKG;                     // BN*BKG = 16KB
  float* gt = (float*)smem;                               // 128 x GSTRIDE fp32
  const int tid  = threadIdx.x;
  const int lane = tid & 63;
  const int wave = tid >> 6;
  const int bn = blockIdx.x * BN;
  const int bm = blockIdx.y * BM;
  const int wm = (wave >> 1) * 64;
  const int wn = (wave & 1) * 64;
  const int K = H_;
  f32x4 acc[4][4];
  #pragma unroll
  for (int mi = 0; mi < 4; mi++)
    #pragma unroll
    for (int ni = 0; ni < 4; ni++) acc[mi][ni] = (f32x4){0.f, 0.f, 0.f, 0.f};

  // staging indices: 1024 16B-chunks per matrix, 4 per thread
  int rr[4], cc[4];
  #pragma unroll
  for (int i = 0; i < 4; i++) {
    int g = i * 256 + tid;
    rr[i] = g >> 3;
    cc[i] = ((g & 7) ^ (rr[i] & 7)) * 8;   // element offset of logical chunk
  }
  const int ar = lane & 15, kqi = lane >> 4;

  for (int k0 = 0; k0 < K; k0 += BKG) {
    #pragma unroll
    for (int i = 0; i < 4; i++)
      async_copy16(A + (size_t)(bm + rr[i]) * K + k0 + cc[i], &As[(i * 256 + tid) * 8]);
    #pragma unroll
    for (int i = 0; i < 4; i++)
      async_copy16(Bw + (size_t)(bn + rr[i]) * K + k0 + cc[i], &Bs[(i * 256 + tid) * 8]);
    __syncthreads();
    #pragma unroll
    for (int kh = 0; kh < 2; kh++) {
      bf16x8 af[4], bf[4];
      #pragma unroll
      for (int mi = 0; mi < 4; mi++) {
        int row = wm + mi * 16 + ar;
        af[mi] = *reinterpret_cast<const bf16x8*>(
            &As[row * BKG + (((kh * 4 + kqi) ^ (row & 7)) * 8)]);
      }
      #pragma unroll
      for (int ni = 0; ni < 4; ni++) {
        int row = wn + ni * 16 + ar;
        bf[ni] = *reinterpret_cast<const bf16x8*>(
            &Bs[row * BKG + (((kh * 4 + kqi) ^ (row & 7)) * 8)]);
      }
      #pragma unroll
      for (int mi = 0; mi < 4; mi++)
        #pragma unroll
        for (int ni = 0; ni < 4; ni++)
          acc[mi][ni] = __builtin_amdgcn_mfma_f32_16x16x32_bf16(af[mi], bf[ni], acc[mi][ni], 0, 0, 0);
    }
    __syncthreads();
  }

  // Epilogue. Prefetch hs early so HBM latency overlaps the GLU/LDS phase.
  const int c4 = tid & 15;                 // float4 column within 64
  const int rw = tid >> 4;                 // 0..15
  const size_t obase = (size_t)bm * H_ + (bn >> 1);
  float4 hv[8];
  #pragma unroll
  for (int rep = 0; rep < 8; rep++) {
    int row = rep * 16 + rw;
    hv[rep] = *reinterpret_cast<const float4*>(&hs[obase + (size_t)row * H_ + c4 * 4]);
  }
  // C/D layout: col = lane&15, row = (lane>>4)*4 + reg.
  // Even col p = GLU 'a' (gate j=p/2), odd col p+1 = GLU 'b' — in lane^1, same row.
  #pragma unroll
  for (int ni = 0; ni < 4; ni++) {
    int p  = wn + ni * 16 + (lane & 15);   // local packed col
    int pe = (bn + p) & ~1;
    float bA = bp[pe], bB = bp[pe + 1];
    int jl = p >> 1;                       // local output col (0..63)
    #pragma unroll
    for (int mi = 0; mi < 4; mi++) {
      int row0 = wm + mi * 16 + (lane >> 4) * 4;
      #pragma unroll
      for (int r = 0; r < 4; r++) {
        float v = acc[mi][ni][r];
        float w = __shfl_xor(v, 1, 64);    // partner column's value
        if (!(lane & 1))
          gt[(row0 + r) * GSTRIDE + jl] = (v + bA) / (1.0f + __expf(-(w + bB)));
      }
    }
  }
  __syncthreads();
  #pragma unroll
  for (int rep = 0; rep < 8; rep++) {
    int row = rep * 16 + rw;
    float4 g = *reinterpret_cast<const float4*>(&gt[row * GSTRIDE + c4 * 4]);
    size_t o = obase + (size_t)row * H_ + c4 * 4;
    float4 rv = {hv[rep].x + g.x, hv[rep].y + g.y, hv[rep].z + g.z, hv[rep].w + g.w};
    *reinterpret_cast<float4*>(&out[o]) = rv;
  }
}

extern "C" void kernel_launch(void* const* d_in, const int* in_sizes, int n_in,
                              void* d_out, int out_size, void* d_ws, size_t ws_size,
                              hipStream_t stream) {
  const float* hs    = (const float*)d_in[0];
  const float* mask  = (const float*)d_in[1];
  const float* nw    = (const float*)d_in[2];
  const float* ldt   = (const float*)d_in[3];
  const float* lar   = (const float*)d_in[4];
  const float* aim   = (const float*)d_in[5];
  const float* crl   = (const float*)d_in[6];
  const float* cim   = (const float*)d_in[7];
  const float* Dp    = (const float*)d_in[8];
  const float* outw  = (const float*)d_in[9];
  const float* outb  = (const float*)d_in[10];
  float* out = (float*)d_out;

  size_t off = 0;
  char* ws = (char*)d_ws;
  auto nxt = [&](size_t bytes) -> void* {
    void* p = ws + off; off += (bytes + 255) & ~(size_t)255; return p;
  };
  float* wr   = (float*)nxt(H_ * N_ * 4);
  float* wi   = (float*)nxt(H_ * N_ * 4);
  float* c2r  = (float*)nxt(H_ * N_ * 4);
  float* c2i  = (float*)nxt(H_ * N_ * 4);
  float* wpr  = (float*)nxt(H_ * N_ * 4);
  float* wpi  = (float*)nxt(H_ * N_ * 4);
  float* bpck = (float*)nxt(O2_ * 4);
  float* scale= (float*)nxt((size_t)M_ * 4);
  float* endr = (float*)nxt((size_t)B_ * NC_ * N_ * H_ * 4);
  float* endi = (float*)nxt((size_t)B_ * NC_ * N_ * H_ * 4);
  float* carr = (float*)nxt((size_t)B_ * NC_ * N_ * H_ * 4);
  float* cari = (float*)nxt((size_t)B_ * NC_ * N_ * H_ * 4);
  unsigned short* Wbf = (unsigned short*)nxt((size_t)O2_ * H_ * 2);
  unsigned short* ubf = (unsigned short*)nxt((size_t)M_ * H_ * 2);
  unsigned short* ybf = (unsigned short*)nxt((size_t)M_ * H_ * 2);

  k_prep<<<dim3(O2_ * H_ / 256), dim3(256), 0, stream>>>(ldt, lar, aim, crl, cim,
                                                         outw, outb,
                                                         wr, wi, c2r, c2i, wpr, wpi,
                                                         Wbf, bpck);
  k_scale<<<dim3(M_), dim3(256), 0, stream>>>(hs, mask, scale);
  k_scan1<<<dim3(H_ / 256, NC_, B_), dim3(256), 0, stream>>>(hs, nw, scale, wr, wi,
                                                             endr, endi, ubf);
  k_carry<<<dim3(B_ * N_ * H_ / 256), dim3(256), 0, stream>>>(wpr, wpi, endr, endi, carr, cari);
  k_scan2<<<dim3(H_ / 256, NC_, B_), dim3(256), 0, stream>>>(ubf, wr, wi, c2r, c2i,
                                                             Dp, carr, cari, ybf);
  k_gemm<<<dim3(O2_ / BN, M_ / BM), dim3(256), 0, stream>>>(ybf, Wbf, bpck, hs, out);
}

// Round 5
// 357.012 us; speedup vs baseline: 1.1797x; 1.0171x over previous
//
#include <hip/hip_runtime.h>

// Problem constants (fixed by the reference)
#define B_   4
#define L_   4096
#define H_   1024
#define N_   16
#define CH_  64             // scan chunk length
#define NC_  (L_/CH_)       // 64 chunks
#define M_   (B_*L_)        // 16384 GEMM rows
#define O2_  (2*H_)         // 2048 GEMM cols (packed pairs: 2j <- W[j], 2j+1 <- W[j+1024])
#define EPS_ 1e-6f

typedef __attribute__((ext_vector_type(4))) float  f32x4;
typedef __attribute__((ext_vector_type(8))) __bf16 bf16x8;

__device__ __forceinline__ unsigned short f2bf(float x) {
  union { float f; unsigned int u; } v; v.f = x;
  unsigned int r = v.u + 0x7FFFu + ((v.u >> 16) & 1u);   // RNE
  return (unsigned short)(r >> 16);
}
__device__ __forceinline__ float bf2f(unsigned short x) {
  union { unsigned int u; float f; } v; v.u = ((unsigned int)x) << 16;
  return v.f;
}

__device__ __forceinline__ void async_copy16(const void* g, void* l) {
  __builtin_amdgcn_global_load_lds(
      (const __attribute__((address_space(1))) unsigned int*)g,
      (__attribute__((address_space(3))) unsigned int*)l, 16, 0, 0);
}

// ---------------- K0: fused prep — SSM params + W pack->bf16 + bias pack ----
// W pack: Wp[2j][h]=W[j][h], Wp[2j+1][h]=W[j+1024][h]  (GLU partners adjacent)
__global__ void k_prep(const float* __restrict__ log_dt,
                       const float* __restrict__ log_A_real,
                       const float* __restrict__ A_imag,
                       const float* __restrict__ C_real,
                       const float* __restrict__ C_imag,
                       const float* __restrict__ outw,
                       const float* __restrict__ outb,
                       float* __restrict__ wr,  float* __restrict__ wi,
                       float* __restrict__ c2r, float* __restrict__ c2i,
                       float* __restrict__ wpr, float* __restrict__ wpi,
                       unsigned short* __restrict__ Wbf,
                       float* __restrict__ bp) {
  int idx = blockIdx.x * 256 + threadIdx.x;      // O2_*H_ threads
  int p = idx >> 10, hh = idx & (H_ - 1);
  size_t src = (size_t)((p >> 1) + (p & 1) * H_) * H_ + hh;
  Wbf[idx] = f2bf(outw[src]);
  if (idx < O2_) bp[idx] = outb[(idx >> 1) + (idx & 1) * H_];
  if (idx < H_ * N_) {
    int h = idx / N_, n = idx % N_;
    int hn = h * N_ + n;
    float dt  = expf(log_dt[h]);
    float Ar  = -expf(log_A_real[hn]);
    float Ai  = A_imag[hn];
    float dr  = Ar * dt, di = Ai * dt;          // dtA
    float er  = expf(dr);
    float wrv = er * cosf(di), wiv = er * sinf(di);   // w = exp(dtA)
    float e1r = wrv - 1.0f, e1i = wiv;                // exp(dtA)-1
    float den = Ar * Ar + Ai * Ai;
    float qr  = (e1r * Ar + e1i * Ai) / den;          // (exp(dtA)-1)/A
    float qi  = (e1i * Ar - e1r * Ai) / den;
    float Cr  = C_real[hn], Ci = C_imag[hn];
    float cdr = Cr * qr - Ci * qi;
    float cdi = Cr * qi + Ci * qr;
    float ep  = expf((float)CH_ * dr);
    int o = n * H_ + h;                                // [n][h] (lane-coalesced)
    wr[o]  = wrv;  wi[o]  = wiv;
    c2r[o] = 2.0f * cdr; c2i[o] = 2.0f * cdi;
    wpr[o] = ep * cosf((float)CH_ * di);
    wpi[o] = ep * sinf((float)CH_ * di);
  }
}

// ---------------- K1: per-row RMSNorm scale = rsqrt(mean(h^2)+eps)*mask -----
__global__ __launch_bounds__(256) void k_scale(const float* __restrict__ hs,
                                               const float* __restrict__ mask,
                                               float* __restrict__ scale) {
  int m = blockIdx.x, tid = threadIdx.x;
  float4 v = reinterpret_cast<const float4*>(hs + (size_t)m * H_)[tid];
  float s = v.x * v.x + v.y * v.y + v.z * v.z + v.w * v.w;
  #pragma unroll
  for (int off = 32; off > 0; off >>= 1) s += __shfl_down(s, off, 64);
  __shared__ float ps[4];
  if ((tid & 63) == 0) ps[tid >> 6] = s;
  __syncthreads();
  if (tid == 0) {
    float var = (ps[0] + ps[1] + ps[2] + ps[3]) * (1.0f / H_);
    scale[m] = rsqrtf(var + EPS_) * mask[m];
  }
}

// ---------------- K2: pass 1 — local end states + u (bf16) ------------------
__global__ __launch_bounds__(256) void k_scan1(const float* __restrict__ hs,
                                               const float* __restrict__ nw,
                                               const float* __restrict__ scale,
                                               const float* __restrict__ wr_,
                                               const float* __restrict__ wi_,
                                               float* __restrict__ endr,
                                               float* __restrict__ endi,
                                               unsigned short* __restrict__ ubf) {
  int tid = threadIdx.x;
  int h = blockIdx.x * 256 + tid;
  int c = blockIdx.y, b = blockIdx.z;
  float wr[N_], wi[N_], xr[N_], xi[N_];
  #pragma unroll
  for (int n = 0; n < N_; n++) {
    wr[n] = wr_[n * H_ + h]; wi[n] = wi_[n * H_ + h];
    xr[n] = 0.f; xi[n] = 0.f;
  }
  float nwh = nw[h];
  int l0 = c * CH_;
  const float* scp = scale + (size_t)b * L_ + l0;   // block-uniform per l
  const float* hp = hs + ((size_t)b * L_ + l0) * H_ + h;
  unsigned short* up = ubf + ((size_t)b * L_ + l0) * H_ + h;
  #pragma unroll 8
  for (int l = 0; l < CH_; l++) {
    float u = hp[(size_t)l * H_] * scp[l] * nwh;
    unsigned short ub = f2bf(u);
    up[(size_t)l * H_] = ub;
    u = bf2f(ub);                 // keep scan consistent with stored u
    #pragma unroll
    for (int n = 0; n < N_; n++) {
      float oxr = xr[n];
      xr[n] = fmaf(wr[n], oxr, fmaf(-wi[n], xi[n], u));
      xi[n] = fmaf(wr[n], xi[n], wi[n] * oxr);
    }
  }
  size_t base = (((size_t)b * NC_ + c) * N_) * H_ + h;
  #pragma unroll
  for (int n = 0; n < N_; n++) {
    endr[base + (size_t)n * H_] = xr[n];
    endi[base + (size_t)n * H_] = xi[n];
  }
}

// ---------------- K3: pass 2 — carry scan, parallel over (b,n,h) ------------
__global__ __launch_bounds__(256) void k_carry(const float* __restrict__ wpr_,
                                               const float* __restrict__ wpi_,
                                               const float* __restrict__ endr,
                                               const float* __restrict__ endi,
                                               float* __restrict__ carr,
                                               float* __restrict__ cari) {
  int idx = blockIdx.x * 256 + threadIdx.x;   // B_*N_*H_ = 65536
  int h = idx & (H_ - 1);
  int n = (idx >> 10) & (N_ - 1);
  int b = idx >> 14;
  float wprv = wpr_[n * H_ + h], wpiv = wpi_[n * H_ + h];
  float sr = 0.f, si = 0.f;
  size_t cstride = (size_t)N_ * H_;
  size_t base = ((size_t)b * NC_) * cstride + (size_t)n * H_ + h;
  for (int c = 0; c < NC_; c++, base += cstride) {
    carr[base] = sr; cari[base] = si;
    float er = endr[base], ei = endi[base];
    float osr = sr;
    sr = fmaf(wprv, osr,  fmaf(-wpiv, si, er));
    si = fmaf(wprv, si, fmaf(wpiv, osr, ei));
  }
}

// ---------------- K4: pass 3 — n-outer re-scan from LDS u-tile --------------
// Stage u[64 l x 256 h] (bf16, 32KB) via global_load_lds, then for each n
// (outer, serial) run the recurrence with 6 live regs, accumulating into
// yacc[CH_]. Register state ~85 (vs ~140 for n-inner) -> better occupancy,
// and all inner-loop reads are LDS (no global-latency stalls).
__global__ __launch_bounds__(256) void k_scan2(const unsigned short* __restrict__ ubf,
                                               const float* __restrict__ wr_,
                                               const float* __restrict__ wi_,
                                               const float* __restrict__ c2r_,
                                               const float* __restrict__ c2i_,
                                               const float* __restrict__ Dp,
                                               const float* __restrict__ carr,
                                               const float* __restrict__ cari,
                                               unsigned short* __restrict__ ybf) {
  __shared__ __align__(16) unsigned short us[CH_ * 256];   // 32KB
  int tid = threadIdx.x;
  int hb = blockIdx.x;                 // h-block (4 of 256)
  int c = blockIdx.y, b = blockIdx.z;
  int h = hb * 256 + tid;
  int l0 = c * CH_;
  const unsigned short* usrc = ubf + ((size_t)b * L_ + l0) * H_ + hb * 256;
  // stage 64x256 bf16 tile: 2048 16B-chunks, 8 per thread; LDS dst is
  // lane-contiguous in g order (required by global_load_lds semantics)
  #pragma unroll
  for (int i = 0; i < 8; i++) {
    int g = i * 256 + tid;
    int l = g >> 5, hq = (g & 31) * 8;
    async_copy16(usrc + (size_t)l * H_ + hq, &us[g * 8]);
  }
  __syncthreads();

  float yacc[CH_];
  float Dh = Dp[h];
  #pragma unroll
  for (int l = 0; l < CH_; l++)
    yacc[l] = Dh * bf2f(us[l * 256 + tid]);

  size_t base = (((size_t)b * NC_ + c) * N_) * H_ + h;
  for (int n = 0; n < N_; n++) {
    float wrv = wr_[n * H_ + h],  wiv = wi_[n * H_ + h];
    float crv = c2r_[n * H_ + h], civ = c2i_[n * H_ + h];
    float xr = carr[base + (size_t)n * H_];
    float xi = cari[base + (size_t)n * H_];
    #pragma unroll
    for (int l = 0; l < CH_; l++) {
      float u = bf2f(us[l * 256 + tid]);
      float oxr = xr;
      xr = fmaf(wrv, oxr, fmaf(-wiv, xi, u));
      xi = fmaf(wrv, xi, wiv * oxr);
      yacc[l] = fmaf(crv, xr, fmaf(-civ, xi, yacc[l]));
    }
  }
  unsigned short* yp = ybf + ((size_t)b * L_ + l0) * H_ + h;
  #pragma unroll
  for (int l = 0; l < CH_; l++) {
    float yv = yacc[l];
    // exact GELU: 0.5*y*(1+erf(y/sqrt(2)))
    float g = 0.5f * yv * (1.0f + erff(yv * 0.70710678118654752f));
    yp[(size_t)l * H_] = f2bf(g);
  }
}

// ---------------- K5: GEMM + fused GLU/bias/residual epilogue ---------------
// Zp[m,p] = y[m,:]·Wp[p,:]; GLU pairs are adjacent columns (p even = a, odd = b).
// BK=64: 32KB staging per iter, 16 K-iterations. LDS swizzle: physical chunk
// g&7 of row r holds logical chunk (g&7)^(r&7); reads use (kh*4+kqi)^(r&7).
// No hs prefetch: keeps peak VGPR low (acc=64 AGPRs already) for 3 blocks/CU.
#define BM 128
#define BN 128
#define BKG 64
#define GSTRIDE 68          // fp32 row stride of g-tile (pad, 16B-aligned)
__global__ __launch_bounds__(256) void k_gemm(const unsigned short* __restrict__ A,
                                              const unsigned short* __restrict__ Bw,
                                              const float* __restrict__ bp,
                                              const float* __restrict__ hs,
                                              float* __restrict__ out) {
  __shared__ __align__(16) char smem[BM * GSTRIDE * 4];   // 34816 B
  unsigned short* As = (unsigned short*)smem;             // BM*BKG = 16KB
  unsigned short* Bs = As + BM * BKG;                     // BN*BKG = 16KB
  float* gt = (float*)smem;                               // 128 x GSTRIDE fp32
  const int tid  = threadIdx.x;
  const int lane = tid & 63;
  const int wave = tid >> 6;
  const int bn = blockIdx.x * BN;
  const int bm = blockIdx.y * BM;
  const int wm = (wave >> 1) * 64;
  const int wn = (wave & 1) * 64;
  const int K = H_;
  f32x4 acc[4][4];
  #pragma unroll
  for (int mi = 0; mi < 4; mi++)
    #pragma unroll
    for (int ni = 0; ni < 4; ni++) acc[mi][ni] = (f32x4){0.f, 0.f, 0.f, 0.f};

  // staging indices: 1024 16B-chunks per matrix, 4 per thread
  int rr[4], cc[4];
  #pragma unroll
  for (int i = 0; i < 4; i++) {
    int g = i * 256 + tid;
    rr[i] = g >> 3;
    cc[i] = ((g & 7) ^ (rr[i] & 7)) * 8;   // element offset of logical chunk
  }
  const int ar = lane & 15, kqi = lane >> 4;

  for (int k0 = 0; k0 < K; k0 += BKG) {
    #pragma unroll
    for (int i = 0; i < 4; i++)
      async_copy16(A + (size_t)(bm + rr[i]) * K + k0 + cc[i], &As[(i * 256 + tid) * 8]);
    #pragma unroll
    for (int i = 0; i < 4; i++)
      async_copy16(Bw + (size_t)(bn + rr[i]) * K + k0 + cc[i], &Bs[(i * 256 + tid) * 8]);
    __syncthreads();
    #pragma unroll
    for (int kh = 0; kh < 2; kh++) {
      bf16x8 af[4], bf[4];
      #pragma unroll
      for (int mi = 0; mi < 4; mi++) {
        int row = wm + mi * 16 + ar;
        af[mi] = *reinterpret_cast<const bf16x8*>(
            &As[row * BKG + (((kh * 4 + kqi) ^ (row & 7)) * 8)]);
      }
      #pragma unroll
      for (int ni = 0; ni < 4; ni++) {
        int row = wn + ni * 16 + ar;
        bf[ni] = *reinterpret_cast<const bf16x8*>(
            &Bs[row * BKG + (((kh * 4 + kqi) ^ (row & 7)) * 8)]);
      }
      #pragma unroll
      for (int mi = 0; mi < 4; mi++)
        #pragma unroll
        for (int ni = 0; ni < 4; ni++)
          acc[mi][ni] = __builtin_amdgcn_mfma_f32_16x16x32_bf16(af[mi], bf[ni], acc[mi][ni], 0, 0, 0);
    }
    __syncthreads();
  }

  // C/D layout: col = lane&15, row = (lane>>4)*4 + reg.
  // Even col p = GLU 'a' (gate j=p/2), odd col p+1 = GLU 'b' — in lane^1, same row.
  #pragma unroll
  for (int ni = 0; ni < 4; ni++) {
    int p  = wn + ni * 16 + (lane & 15);   // local packed col
    int pe = (bn + p) & ~1;
    float bA = bp[pe], bB = bp[pe + 1];
    int jl = p >> 1;                       // local output col (0..63)
    #pragma unroll
    for (int mi = 0; mi < 4; mi++) {
      int row0 = wm + mi * 16 + (lane >> 4) * 4;
      #pragma unroll
      for (int r = 0; r < 4; r++) {
        float v = acc[mi][ni][r];
        float w = __shfl_xor(v, 1, 64);    // partner column's value
        if (!(lane & 1))
          gt[(row0 + r) * GSTRIDE + jl] = (v + bA) / (1.0f + __expf(-(w + bB)));
      }
    }
  }
  __syncthreads();
  {
    const int c4 = tid & 15;               // float4 column within 64
    const int rw = tid >> 4;               // 0..15
    const size_t obase = (size_t)bm * H_ + (bn >> 1);
    #pragma unroll
    for (int rep = 0; rep < 8; rep++) {
      int row = rep * 16 + rw;
      float4 g = *reinterpret_cast<const float4*>(&gt[row * GSTRIDE + c4 * 4]);
      size_t o = obase + (size_t)row * H_ + c4 * 4;
      float4 hv = *reinterpret_cast<const float4*>(&hs[o]);
      float4 rv = {hv.x + g.x, hv.y + g.y, hv.z + g.z, hv.w + g.w};
      *reinterpret_cast<float4*>(&out[o]) = rv;
    }
  }
}

extern "C" void kernel_launch(void* const* d_in, const int* in_sizes, int n_in,
                              void* d_out, int out_size, void* d_ws, size_t ws_size,
                              hipStream_t stream) {
  const float* hs    = (const float*)d_in[0];
  const float* mask  = (const float*)d_in[1];
  const float* nw    = (const float*)d_in[2];
  const float* ldt   = (const float*)d_in[3];
  const float* lar   = (const float*)d_in[4];
  const float* aim   = (const float*)d_in[5];
  const float* crl   = (const float*)d_in[6];
  const float* cim   = (const float*)d_in[7];
  const float* Dp    = (const float*)d_in[8];
  const float* outw  = (const float*)d_in[9];
  const float* outb  = (const float*)d_in[10];
  float* out = (float*)d_out;

  size_t off = 0;
  char* ws = (char*)d_ws;
  auto nxt = [&](size_t bytes) -> void* {
    void* p = ws + off; off += (bytes + 255) & ~(size_t)255; return p;
  };
  float* wr   = (float*)nxt(H_ * N_ * 4);
  float* wi   = (float*)nxt(H_ * N_ * 4);
  float* c2r  = (float*)nxt(H_ * N_ * 4);
  float* c2i  = (float*)nxt(H_ * N_ * 4);
  float* wpr  = (float*)nxt(H_ * N_ * 4);
  float* wpi  = (float*)nxt(H_ * N_ * 4);
  float* bpck = (float*)nxt(O2_ * 4);
  float* scale= (float*)nxt((size_t)M_ * 4);
  float* endr = (float*)nxt((size_t)B_ * NC_ * N_ * H_ * 4);
  float* endi = (float*)nxt((size_t)B_ * NC_ * N_ * H_ * 4);
  float* carr = (float*)nxt((size_t)B_ * NC_ * N_ * H_ * 4);
  float* cari = (float*)nxt((size_t)B_ * NC_ * N_ * H_ * 4);
  unsigned short* Wbf = (unsigned short*)nxt((size_t)O2_ * H_ * 2);
  unsigned short* ubf = (unsigned short*)nxt((size_t)M_ * H_ * 2);
  unsigned short* ybf = (unsigned short*)nxt((size_t)M_ * H_ * 2);

  k_prep<<<dim3(O2_ * H_ / 256), dim3(256), 0, stream>>>(ldt, lar, aim, crl, cim,
                                                         outw, outb,
                                                         wr, wi, c2r, c2i, wpr, wpi,
                                                         Wbf, bpck);
  k_scale<<<dim3(M_), dim3(256), 0, stream>>>(hs, mask, scale);
  k_scan1<<<dim3(H_ / 256, NC_, B_), dim3(256), 0, stream>>>(hs, nw, scale, wr, wi,
                                                             endr, endi, ubf);
  k_carry<<<dim3(B_ * N_ * H_ / 256), dim3(256), 0, stream>>>(wpr, wpi, endr, endi, carr, cari);
  k_scan2<<<dim3(H_ / 256, NC_, B_), dim3(256), 0, stream>>>(ubf, wr, wi, c2r, c2i,
                                                             Dp, carr, cari, ybf);
  k_gemm<<<dim3(O2_ / BN, M_ / BM), dim3(256), 0, stream>>>(ybf, Wbf, bpck, hs, out);
}